// Round 1
// baseline (224.147 us; speedup 1.0000x reference)
//
#include <hip/hip_runtime.h>

// Problem constants
constexpr int B = 32, C = 32, T = 2048, D = 512;
constexpr float ALPHA = 0.1f;
constexpr float BETA  = 0.9f;

// EWMA chunking
constexpr int CHUNK = 256;   // t-chunk per block
constexpr int SUB   = 32;    // t per thread
constexpr int HALO  = 128;   // beta^128 ~ 1.4e-6 -> error way below threshold
constexpr int PAD   = 515;   // LDS row pitch (odd*~ -> banks spread; 32*515*4 = 65.9 KB)

// ---------------------------------------------------------------------------
// Kernel 1: W_comb[e,c] = sum_d W_lin[e,d]*W_ve[d,c];
//           b_comb[e]   = sum_d W_lin[e,d]*b_ve[d] + b_lin[e]
// grid = D blocks, 256 threads: c = tid&31, ds = tid>>5 (8 slices of 64 d)
// ---------------------------------------------------------------------------
__global__ __launch_bounds__(256) void combine_weights(
    const float* __restrict__ W_ve, const float* __restrict__ b_ve,
    const float* __restrict__ W_lin, const float* __restrict__ b_lin,
    float* __restrict__ W_comb, float* __restrict__ b_comb) {
  int e  = blockIdx.x;
  int c  = threadIdx.x & 31;
  int ds = threadIdx.x >> 5;
  float acc = 0.f, accb = 0.f;
#pragma unroll 4
  for (int i = 0; i < 64; ++i) {
    int d = ds * 64 + i;
    float wl = W_lin[e * D + d];
    acc  += wl * W_ve[d * C + c];
    accb += wl * b_ve[d];
  }
  __shared__ float red[8][33];
  __shared__ float redb[8];
  red[ds][c] = acc;
  if (c == 0) redb[ds] = accb;
  __syncthreads();
  if (ds == 0) {
    float ssum = 0.f;
#pragma unroll
    for (int k = 0; k < 8; ++k) ssum += red[k][c];
    W_comb[e * C + c] = ssum;
    if (c == 0) {
      float sb = 0.f;
#pragma unroll
      for (int k = 0; k < 8; ++k) sb += redb[k];
      b_comb[e] = sb + b_lin[e];
    }
  }
}

// ---------------------------------------------------------------------------
// Kernel 2: channel-space diff + bidirectional EWMA.
//   d[b,t,c] = (t==0) ? 0 : x[b,c,t]-x[b,c,t-1]
//   lr: fwd EWMA, rl: bwd EWMA, s = 0.5*(lr+rl), layout s[b][t][c]
// grid = (T/CHUNK, B), 256 threads: thread (c = tid&31, sub = tid>>5) owns
// t in [t0+sub*32, +32). Halo of 128 steps approximates the carry-in
// (exact at the true sequence edges).
// ---------------------------------------------------------------------------
__global__ __launch_bounds__(256) void diff_ewma(
    const float* __restrict__ x, float* __restrict__ sdst) {
  int b  = blockIdx.y;
  int t0 = blockIdx.x * CHUNK;
  int wlo = max(t0 - HALO - 1, 0);  // stage window [wlo, wlo+514), clamped

  __shared__ float xl[C * PAD];
  const float* xb = x + (size_t)b * C * T;
  for (int idx = threadIdx.x; idx < C * 514; idx += 256) {
    int c  = idx / 514;          // compile-time divisor
    int tt = idx - c * 514;
    int t  = wlo + tt;
    xl[c * PAD + tt] = (t < T) ? xb[c * T + t] : 0.f;
  }
  __syncthreads();

  int c   = threadIdx.x & 31;
  int sub = threadIdx.x >> 5;
  int ts  = t0 + sub * SUB;
  const float* xc = xl + c * PAD - wlo;  // index directly by global t

#define DD(t) ((t) == 0 ? 0.f : (xc[(t)] - xc[(t) - 1]))

  // forward scan with halo
  float lr[SUB];
  int st = max(ts - HALO, 0);
  float carry = DD(st);                 // lr[st] approx (exact when st==0)
  for (int t = st + 1; t < ts; ++t) carry = ALPHA * DD(t) + BETA * carry;
#pragma unroll
  for (int i = 0; i < SUB; ++i) {
    int t = ts + i;
    if (t > st) carry = ALPHA * DD(t) + BETA * carry;  // t==st only when ts==0
    lr[i] = carry;
  }

  // backward scan with halo, combine + store on the fly
  int en = min(ts + SUB - 1 + HALO, T - 1);  // en >= ts+SUB-1 always
  float rcar = DD(en);                        // rl[en] approx (exact when en==T-1)
  for (int t = en - 1; t >= ts + SUB; --t) rcar = ALPHA * DD(t) + BETA * rcar;
  float* srow = sdst + ((size_t)b * T) * C + c;
#pragma unroll
  for (int i = SUB - 1; i >= 0; --i) {
    int t = ts + i;
    if (t < en) rcar = ALPHA * DD(t) + BETA * rcar;    // skip when t==en
    srow[(size_t)t * C] = 0.5f * (lr[i] + rcar);
  }
#undef DD
}

// ---------------------------------------------------------------------------
// Kernel 3: out[b,t,e] = sum_c s[b,t,c]*W_comb[e,c] + b_comb[e]
// grid = (T/64, B), 256 threads. Thread owns e0=tid, e1=tid+256 with W rows
// in VGPRs; s-row reads are wave-uniform (scalar-load friendly); stores are
// lane->e coalesced. 4 split accumulators for FMA pipelining.
// ---------------------------------------------------------------------------
constexpr int TPB = 64;  // t rows per block
__global__ __launch_bounds__(256) void out_gemm(
    const float* __restrict__ s, const float* __restrict__ W_comb,
    const float* __restrict__ b_comb, float* __restrict__ out) {
  int b  = blockIdx.y;
  int t0 = blockIdx.x * TPB;
  int e0 = threadIdx.x;
  int e1 = threadIdx.x + 256;

  float w0[C], w1[C];
#pragma unroll
  for (int c = 0; c < C; ++c) {
    w0[c] = W_comb[e0 * C + c];
    w1[c] = W_comb[e1 * C + c];
  }
  float bb0 = b_comb[e0], bb1 = b_comb[e1];

  const float* srow = s + ((size_t)b * T + t0) * C;
  float* orow = out + ((size_t)b * T + t0) * D;
  for (int t = 0; t < TPB; ++t) {
    float a0 = bb0, a1 = bb1, a2 = 0.f, a3 = 0.f;
#pragma unroll
    for (int c = 0; c < C; c += 2) {
      float sv0 = srow[c], sv1 = srow[c + 1];
      a0 += sv0 * w0[c];
      a1 += sv0 * w1[c];
      a2 += sv1 * w0[c + 1];
      a3 += sv1 * w1[c + 1];
    }
    orow[e0] = a0 + a2;
    orow[e1] = a1 + a3;
    srow += C;
    orow += D;
  }
}

// ---------------------------------------------------------------------------
extern "C" void kernel_launch(void* const* d_in, const int* in_sizes, int n_in,
                              void* d_out, int out_size, void* d_ws, size_t ws_size,
                              hipStream_t stream) {
  const float* x     = (const float*)d_in[0];  // [B,C,T]
  const float* W_ve  = (const float*)d_in[1];  // [D,C]
  const float* b_ve  = (const float*)d_in[2];  // [D]
  const float* W_lin = (const float*)d_in[3];  // [D,D]
  const float* b_lin = (const float*)d_in[4];  // [D]
  float* out = (float*)d_out;                  // [B,T,D]

  // workspace layout: s [B*T*C] fp32, W_comb [D*C], b_comb [D]  (~8.5 MB)
  float* s      = (float*)d_ws;
  float* W_comb = s + (size_t)B * T * C;
  float* b_comb = W_comb + (size_t)D * C;

  combine_weights<<<D, 256, 0, stream>>>(W_ve, b_ve, W_lin, b_lin, W_comb, b_comb);
  diff_ewma<<<dim3(T / CHUNK, B), 256, 0, stream>>>(x, s);
  out_gemm<<<dim3(T / TPB, B), 256, 0, stream>>>(s, W_comb, b_comb, out);
}